// Round 3
// baseline (158.372 us; speedup 1.0000x reference)
//
#include <hip/hip_runtime.h>
#include <hip/hip_bf16.h>

#define NPTS 2048
#define BATCH 16
#define TILE 256
#define NT (NPTS / TILE)   // 8 tiles -> 36 (ci<=cj) tile pairs

// ---------------------------------------------------------------------------
// Kernel 1: per-batch MLP (h = relu(pos_flat@W1.T+b1), z = tanh(h@W2.T+b2)),
// rigid transforms R/T per segment, then transform all points + color softmax.
// Also zeroes the reg accumulators (reg slots of d_out).
// One block per batch element.
// ---------------------------------------------------------------------------
__global__ __launch_bounds__(256) void k_mlp_transform(
    const float* __restrict__ x, const float* __restrict__ W1,
    const float* __restrict__ b1, const float* __restrict__ W2,
    const float* __restrict__ b2, const float* __restrict__ center,
    const float* __restrict__ sz, float* __restrict__ out)
{
    const int b = blockIdx.x;
    const int t = threadIdx.x;

    __shared__ float hbuf[32];
    __shared__ float zbuf[18];
    __shared__ float Rl[3][9];   // Rl[s][m*3+n] = XYZ[m][n]
    __shared__ float Tl[3][3];

    // ---- h: 32 units, 8 threads each over 6144-length dot (float4 loads) ----
    {
        const int j = t >> 3;           // hidden unit 0..31
        const int l = t & 7;            // lane within unit
        const float4* xb4 = reinterpret_cast<const float4*>(x + (size_t)b * 12288);
        const float4* wj4 = reinterpret_cast<const float4*>(W1 + (size_t)j * 6144);
        float dot = 0.f;
        #pragma unroll 4
        for (int k = l; k < 1536; k += 8) {
            float4 a = xb4[k];
            float4 w = wj4[k];
            dot += a.x * w.x + a.y * w.y + a.z * w.z + a.w * w.w;
        }
        dot += __shfl_xor(dot, 1);
        dot += __shfl_xor(dot, 2);
        dot += __shfl_xor(dot, 4);
        if (l == 0) hbuf[j] = fmaxf(dot + b1[j], 0.f);
    }
    // zero the reg accumulator for this batch (reg slots of out; k_reg runs after)
    if (t == 0) out[196608 + b] = 0.f;
    __syncthreads();

    // ---- z = tanh(h @ W2.T + b2), 18 outputs ----
    if (t < 18) {
        float s = b2[t];
        #pragma unroll
        for (int j = 0; j < 32; ++j) s += hbuf[j] * W2[t * 32 + j];
        zbuf[t] = tanhf(s);
    }
    __syncthreads();

    // ---- rigid transform per segment (3 threads) ----
    if (t < 3) {
        const int s = t;
        const float PI = 3.14159265358979323846f;
        float a0 = PI * zbuf[s * 6 + 3];
        float a1 = PI * zbuf[s * 6 + 4];
        float a2 = PI * zbuf[s * 6 + 5];
        float c0 = cosf(a0), s0 = sinf(a0);
        float c1 = cosf(a1), s1 = sinf(a1);
        float c2 = cosf(a2), s2 = sinf(a2);
        float X[3][3] = {{c0, -s0, 0.f}, {s0, c0, 0.f}, {0.f, 0.f, 1.f}};
        float Y[3][3] = {{c1, 0.f, s1}, {0.f, 1.f, 0.f}, {-s1, 0.f, c1}};
        float Z[3][3] = {{1.f, 0.f, 0.f}, {0.f, c2, -s2}, {0.f, s2, c2}};
        float YZ[3][3], M[3][3];
        for (int m = 0; m < 3; ++m)
            for (int n = 0; n < 3; ++n) {
                float v = 0.f;
                for (int k = 0; k < 3; ++k) v += Y[m][k] * Z[k][n];
                YZ[m][n] = v;
            }
        for (int m = 0; m < 3; ++m)
            for (int n = 0; n < 3; ++n) {
                float v = 0.f;
                for (int k = 0; k < 3; ++k) v += X[m][k] * YZ[k][n];
                M[m][n] = v;
                Rl[s][m * 3 + n] = v;
            }
        for (int sd = 0; sd < 3; ++sd) {
            float tr = zbuf[s * 6 + 3 + sd];  // trans = z_l[:,:,3:]
            Tl[s][sd] = tr * sz[sd] + center[sd]
                      - (center[0] * M[0][sd] + center[1] * M[1][sd] + center[2] * M[2][sd]);
        }
    }
    __syncthreads();

    // ---- transform points (pos_t = M^T p + T) and color softmax ----
    const float* xb = x + (size_t)b * 12288;
    float* ob = out + (size_t)b * 12288;
    for (int n = t; n < 2048; n += 256) {
        float px = xb[n], py = xb[2048 + n], pz = xb[4096 + n];
        int s = (n < 20) ? 0 : (n < 40) ? 1 : 2;
        #pragma unroll
        for (int td = 0; td < 3; ++td) {
            float v = Rl[s][0 * 3 + td] * px + Rl[s][1 * 3 + td] * py
                    + Rl[s][2 * 3 + td] * pz + Tl[s][td];
            ob[td * 2048 + n] = v;
        }
        float c3 = xb[6144 + n], c4 = xb[8192 + n], c5 = xb[10240 + n];
        float mx = fmaxf(c3, fmaxf(c4, c5));
        float e3 = __expf(c3 - mx), e4 = __expf(c4 - mx), e5 = __expf(c5 - mx);
        float inv = 1.f / (e3 + e4 + e5);
        ob[6144 + n] = e3 * inv;
        ob[8192 + n] = e4 * inv;
        ob[10240 + n] = e5 * inv;
    }
}

// ---------------------------------------------------------------------------
// Kernel 2: reg partial sums. Triangle-tiled: 36 tile pairs (ci<=cj) of
// 256x256 over the symmetric (dA-dx) matrix; contribution predicate j>i is
// automatically true for off-diagonal tiles. One i per thread (registers),
// j-tile staged in LDS as float4 pairs (broadcast reads, conflict-free).
// atomicAdd one partial per block into out[196608+b].
// ---------------------------------------------------------------------------
__global__ __launch_bounds__(256) void k_reg(
    const float* __restrict__ x, const float* __restrict__ A,
    float* __restrict__ out)
{
    const int p = blockIdx.x;   // 0..35
    const int b = blockIdx.y;   // 0..15
    int ci = 0, rem = p;
    while (rem >= NT - ci) { rem -= NT - ci; ++ci; }
    const int cj = ci + rem;
    const int t = threadIdx.x;

    __shared__ float4 pj[TILE];
    __shared__ float4 aj[TILE];

    const float* xb = x + (size_t)b * 12288;
    {
        int j = cj * TILE + t;
        pj[t] = make_float4(xb[j], xb[2048 + j], xb[4096 + j], 0.f);
        aj[t] = make_float4(A[j], A[2048 + j], A[4096 + j], 0.f);
    }
    __syncthreads();

    const int i = ci * TILE + t;
    const float pix = xb[i], piy = xb[2048 + i], piz = xb[4096 + i];
    const float aix = A[i], aiy = A[2048 + i], aiz = A[4096 + i];
    const int jbase = cj * TILE;

    float acc = 0.f;
    #pragma unroll 4
    for (int jj = 0; jj < TILE; ++jj) {
        float4 P = pj[jj];
        float4 Q = aj[jj];
        float dx0 = pix - P.x, dy0 = piy - P.y, dz0 = piz - P.z;
        float d2x = dx0 * dx0 + dy0 * dy0 + dz0 * dz0;
        float dxv = sqrtf(d2x);
        float da0 = aix - Q.x, da1 = aiy - Q.y, da2 = aiz - Q.z;
        float d2a = da0 * da0 + da1 * da1 + da2 * da2;
        float dav = sqrtf(d2a);
        float d = dav - dxv;
        float dd = (jbase + jj > i) ? d : 0.f;  // strict upper triangle
        acc = fmaf(dd, dd, acc);
    }

    // wave reduce (64 lanes) then cross-wave via LDS
    acc += __shfl_xor(acc, 1);
    acc += __shfl_xor(acc, 2);
    acc += __shfl_xor(acc, 4);
    acc += __shfl_xor(acc, 8);
    acc += __shfl_xor(acc, 16);
    acc += __shfl_xor(acc, 32);
    __shared__ float wsum[4];
    if ((t & 63) == 0) wsum[t >> 6] = acc;
    __syncthreads();
    if (t == 0) {
        float s = wsum[0] + wsum[1] + wsum[2] + wsum[3];
        atomicAdd(&out[196608 + b], s);
    }
}

// ---------------------------------------------------------------------------
// Kernel 3: reg[b] = sqrt(2 * acc[b])   (upper triangle doubled; diag is 0)
// ---------------------------------------------------------------------------
__global__ void k_final(float* __restrict__ out)
{
    int b = threadIdx.x;
    if (b < BATCH) {
        float v = out[196608 + b];
        out[196608 + b] = sqrtf(2.f * v);
    }
}

extern "C" void kernel_launch(void* const* d_in, const int* in_sizes, int n_in,
                              void* d_out, int out_size, void* d_ws, size_t ws_size,
                              hipStream_t stream) {
    (void)in_sizes; (void)n_in; (void)d_ws; (void)ws_size; (void)out_size;
    const float* x      = (const float*)d_in[0];
    const float* W1     = (const float*)d_in[1];
    const float* b1     = (const float*)d_in[2];
    const float* W2     = (const float*)d_in[3];
    const float* b2     = (const float*)d_in[4];
    const float* A      = (const float*)d_in[5];
    const float* center = (const float*)d_in[6];
    const float* sz     = (const float*)d_in[7];
    float* out = (float*)d_out;

    k_mlp_transform<<<BATCH, 256, 0, stream>>>(x, W1, b1, W2, b2, center, sz, out);
    k_reg<<<dim3(36, BATCH), 256, 0, stream>>>(x, A, out);
    k_final<<<1, 64, 0, stream>>>(out);
}

// Round 4
// 107.407 us; speedup vs baseline: 1.4745x; 1.4745x over previous
//
#include <hip/hip_runtime.h>
#include <hip/hip_bf16.h>

#define NPTS 2048
#define BATCH 16
#define REG_BASE 196608   // out offset of reg[16]

// ---- ws layout (floats) ----
#define H_OFF    0                       // h[16][32]
#define RT_OFF   512                     // rt[16][3][12]  (R 9 + T 3)
#define MOM_OFF  1088                    // mom[17][4] = {sx,sy,sz,s2}; idx16 = A
#define POSW_OFF 1280                    // float4 posw[16][2048]
#define AW_OFF   (POSW_OFF + 16*2048*4)  // float4 aw[2048]
#define WS_FLOATS (AW_OFF + 2048*4)
#define WS_BYTES  ((size_t)WS_FLOATS * 4)

// ===========================================================================
// FAST PATH
// ===========================================================================

// ---- k_h: h[b][j] = relu(x_pos[b] . W1[j] + b1[j]); also zero accumulators.
// grid (4 jg, 16 b), 256 thr: 8 units/block, 32 lanes/unit.
__global__ __launch_bounds__(256) void k_h(
    const float* __restrict__ x, const float* __restrict__ W1,
    const float* __restrict__ b1, float* __restrict__ out,
    float* __restrict__ ws)
{
    const int jg = blockIdx.x, b = blockIdx.y;
    const int t = threadIdx.x;
    const int j = jg * 8 + (t >> 5);   // hidden unit
    const int l = t & 31;

    if (jg == 0 && b == 0) {           // zero reg slots + moments (ws poisoned)
        if (t < BATCH) out[REG_BASE + t] = 0.f;
        if (t < 68) ws[MOM_OFF + t] = 0.f;
    }

    const float4* xb4 = reinterpret_cast<const float4*>(x + (size_t)b * 12288);
    const float4* wj4 = reinterpret_cast<const float4*>(W1 + (size_t)j * 6144);
    float dot = 0.f;
    #pragma unroll 4
    for (int k = l; k < 1536; k += 32) {
        float4 a = xb4[k];
        float4 w = wj4[k];
        dot += a.x * w.x + a.y * w.y + a.z * w.z + a.w * w.w;
    }
    dot += __shfl_xor(dot, 1, 32);
    dot += __shfl_xor(dot, 2, 32);
    dot += __shfl_xor(dot, 4, 32);
    dot += __shfl_xor(dot, 8, 32);
    dot += __shfl_xor(dot, 16, 32);
    if (l == 0) ws[H_OFF + b * 32 + j] = fmaxf(dot + b1[j], 0.f);
}

// ---- k_zr: z (only the 3 used comps per segment) + rigid R/T. 1 block.
__global__ __launch_bounds__(64) void k_zr(
    const float* __restrict__ W2, const float* __restrict__ b2,
    const float* __restrict__ center, const float* __restrict__ sz,
    float* __restrict__ ws)
{
    const int t = threadIdx.x;
    if (t >= 48) return;
    const int b = t / 3, s = t % 3;
    const float* hb = ws + H_OFF + b * 32;

    float z[3];
    #pragma unroll
    for (int d = 0; d < 3; ++d) {
        const int row = s * 6 + 3 + d;
        float acc = b2[row];
        #pragma unroll
        for (int j = 0; j < 32; ++j) acc += hb[j] * W2[row * 32 + j];
        z[d] = tanhf(acc);
    }
    const float PI = 3.14159265358979323846f;
    float c0 = cosf(PI * z[0]), s0 = sinf(PI * z[0]);
    float c1 = cosf(PI * z[1]), s1 = sinf(PI * z[1]);
    float c2 = cosf(PI * z[2]), s2 = sinf(PI * z[2]);
    float X[3][3] = {{c0, -s0, 0.f}, {s0, c0, 0.f}, {0.f, 0.f, 1.f}};
    float Y[3][3] = {{c1, 0.f, s1}, {0.f, 1.f, 0.f}, {-s1, 0.f, c1}};
    float Z[3][3] = {{1.f, 0.f, 0.f}, {0.f, c2, -s2}, {0.f, s2, c2}};
    float YZ[3][3], M[3][3];
    for (int m = 0; m < 3; ++m)
        for (int n = 0; n < 3; ++n) {
            float v = 0.f;
            for (int k = 0; k < 3; ++k) v += Y[m][k] * Z[k][n];
            YZ[m][n] = v;
        }
    float* rt = ws + RT_OFF + (b * 3 + s) * 12;
    for (int m = 0; m < 3; ++m)
        for (int n = 0; n < 3; ++n) {
            float v = 0.f;
            for (int k = 0; k < 3; ++k) v += X[m][k] * YZ[k][n];
            M[m][n] = v;
            rt[m * 3 + n] = v;
        }
    for (int d = 0; d < 3; ++d)
        rt[9 + d] = z[d] * sz[d] + center[d]
                  - (center[0] * M[0][d] + center[1] * M[1][d] + center[2] * M[2][d]);
}

// ---- k_transform: X_t (transform + softmax), pack posw/aw, moments.
// grid (8 chunks, 17 b) — b==16 handles A. 256 thr.
__global__ __launch_bounds__(256) void k_transform(
    const float* __restrict__ x, const float* __restrict__ A,
    float* __restrict__ out, float* __restrict__ ws)
{
    const int c = blockIdx.x, b = blockIdx.y;
    const int t = threadIdx.x;
    const int n = c * 256 + t;
    float4* posw = reinterpret_cast<float4*>(ws + POSW_OFF);
    float4* aw   = reinterpret_cast<float4*>(ws + AW_OFF);

    float px, py, pz;
    if (b < BATCH) {
        const float* xb = x + (size_t)b * 12288;
        px = xb[n]; py = xb[2048 + n]; pz = xb[4096 + n];
        posw[b * 2048 + n] = make_float4(px, py, pz, 0.f);

        const int s = (n < 20) ? 0 : (n < 40) ? 1 : 2;
        const float* rt = ws + RT_OFF + (b * 3 + s) * 12;
        float* ob = out + (size_t)b * 12288;
        #pragma unroll
        for (int d = 0; d < 3; ++d)
            ob[d * 2048 + n] = rt[0 * 3 + d] * px + rt[1 * 3 + d] * py
                             + rt[2 * 3 + d] * pz + rt[9 + d];

        float c3 = xb[6144 + n], c4 = xb[8192 + n], c5 = xb[10240 + n];
        float mx = fmaxf(c3, fmaxf(c4, c5));
        float e3 = __expf(c3 - mx), e4 = __expf(c4 - mx), e5 = __expf(c5 - mx);
        float inv = 1.f / (e3 + e4 + e5);
        ob[6144 + n] = e3 * inv;
        ob[8192 + n] = e4 * inv;
        ob[10240 + n] = e5 * inv;
    } else {
        px = A[n]; py = A[2048 + n]; pz = A[4096 + n];
        aw[n] = make_float4(px, py, pz, 0.f);
    }

    // moments: {sx, sy, sz, s2}
    float v0 = px, v1 = py, v2 = pz, v3 = px * px + py * py + pz * pz;
    #pragma unroll
    for (int m = 1; m < 64; m <<= 1) {
        v0 += __shfl_xor(v0, m);
        v1 += __shfl_xor(v1, m);
        v2 += __shfl_xor(v2, m);
        v3 += __shfl_xor(v3, m);
    }
    __shared__ float wpart[4][4];
    const int w = t >> 6;
    if ((t & 63) == 0) {
        wpart[w][0] = v0; wpart[w][1] = v1; wpart[w][2] = v2; wpart[w][3] = v3;
    }
    __syncthreads();
    if (t < 4) {
        float s4 = wpart[0][t] + wpart[1][t] + wpart[2][t] + wpart[3][t];
        atomicAdd(&ws[MOM_OFF + b * 4 + t], s4);
    }
}

// ---- k_reg_s: cross[b] = sum_{i<j} sqrt(d2a*d2x), scalar-path j-reads.
// grid (72 = 36 pairs * 2 j-halves, 16 b), 256 thr, 1 i/thread, 128 j/block.
__global__ __launch_bounds__(256) void k_reg_s(
    const float* __restrict__ ws_ro, float* __restrict__ out)
{
    const int bx = blockIdx.x, b = blockIdx.y;
    const int p = bx >> 1, h = bx & 1;
    int ci = 0, rem = p;
    while (rem >= 8 - ci) { rem -= 8 - ci; ++ci; }
    const int cj = ci + rem;
    const int t = threadIdx.x;

    const float4* posw = reinterpret_cast<const float4*>(ws_ro + POSW_OFF);
    const float4* aw   = reinterpret_cast<const float4*>(ws_ro + AW_OFF);

    const int i = ci * 256 + t;
    const int jb = cj * 256 + h * 128;
    float4 Pi = posw[(size_t)b * 2048 + i];
    float4 Ai = aw[i];
    const float pix = Pi.x, piy = Pi.y, piz = Pi.z;
    const float aix = Ai.x, aiy = Ai.y, aiz = Ai.z;

    const float4* pj = posw + (size_t)b * 2048 + jb;  // wave-uniform reads
    const float4* aj = aw + jb;

    float a0 = 0.f, a1 = 0.f, a2 = 0.f, a3 = 0.f;

#define PAIR_BODY(K, ACC, PRED)                                          \
    {                                                                    \
        float4 P = pj[jj + K];                                           \
        float4 Q = aj[jj + K];                                           \
        float ux = pix - P.x, uy = piy - P.y, uz = piz - P.z;            \
        float d2x = ux * ux + uy * uy + uz * uz;                         \
        float vx = aix - Q.x, vy = aiy - Q.y, vz = aiz - Q.z;            \
        float d2a = vx * vx + vy * vy + vz * vz;                         \
        float s = __builtin_amdgcn_sqrtf(d2x * d2a);                     \
        if (PRED) s = (jb + jj + K > i) ? s : 0.f;                       \
        ACC += s;                                                        \
    }

    if (ci != cj) {
        for (int jj = 0; jj < 128; jj += 4) {
            PAIR_BODY(0, a0, false)
            PAIR_BODY(1, a1, false)
            PAIR_BODY(2, a2, false)
            PAIR_BODY(3, a3, false)
        }
    } else {
        for (int jj = 0; jj < 128; jj += 4) {
            PAIR_BODY(0, a0, true)
            PAIR_BODY(1, a1, true)
            PAIR_BODY(2, a2, true)
            PAIR_BODY(3, a3, true)
        }
    }
#undef PAIR_BODY

    float acc = (a0 + a1) + (a2 + a3);
    #pragma unroll
    for (int m = 1; m < 64; m <<= 1) acc += __shfl_xor(acc, m);
    __shared__ float wsum[4];
    if ((t & 63) == 0) wsum[t >> 6] = acc;
    __syncthreads();
    if (t == 0)
        atomicAdd(&out[REG_BASE + b], wsum[0] + wsum[1] + wsum[2] + wsum[3]);
}

// ---- k_final: reg[b] = sqrt(S2a + S2x[b] - 4*cross[b])
__global__ void k_final_s(float* __restrict__ out, const float* __restrict__ ws)
{
    const int b = threadIdx.x;
    if (b >= BATCH) return;
    const float* ma = ws + MOM_OFF + 16 * 4;
    const float* mb = ws + MOM_OFF + b * 4;
    float S2a = 2.f * (2048.f * ma[3] - (ma[0]*ma[0] + ma[1]*ma[1] + ma[2]*ma[2]));
    float S2x = 2.f * (2048.f * mb[3] - (mb[0]*mb[0] + mb[1]*mb[1] + mb[2]*mb[2]));
    float cross = out[REG_BASE + b];
    out[REG_BASE + b] = sqrtf(fmaxf(S2a + S2x - 4.f * cross, 0.f));
}

// ===========================================================================
// FALLBACK PATH (round-3 proven kernels; used only if ws too small)
// ===========================================================================
__global__ __launch_bounds__(256) void k_mlp_fb(
    const float* __restrict__ x, const float* __restrict__ W1,
    const float* __restrict__ b1, const float* __restrict__ W2,
    const float* __restrict__ b2, const float* __restrict__ center,
    const float* __restrict__ sz, float* __restrict__ out)
{
    const int b = blockIdx.x;
    const int t = threadIdx.x;
    __shared__ float hbuf[32];
    __shared__ float zbuf[18];
    __shared__ float Rl[3][9];
    __shared__ float Tl[3][3];
    {
        const int j = t >> 3;
        const int l = t & 7;
        const float4* xb4 = reinterpret_cast<const float4*>(x + (size_t)b * 12288);
        const float4* wj4 = reinterpret_cast<const float4*>(W1 + (size_t)j * 6144);
        float dot = 0.f;
        #pragma unroll 4
        for (int k = l; k < 1536; k += 8) {
            float4 a = xb4[k];
            float4 w = wj4[k];
            dot += a.x * w.x + a.y * w.y + a.z * w.z + a.w * w.w;
        }
        dot += __shfl_xor(dot, 1);
        dot += __shfl_xor(dot, 2);
        dot += __shfl_xor(dot, 4);
        if (l == 0) hbuf[j] = fmaxf(dot + b1[j], 0.f);
    }
    if (t == 0) out[REG_BASE + b] = 0.f;
    __syncthreads();
    if (t < 18) {
        float s = b2[t];
        #pragma unroll
        for (int j = 0; j < 32; ++j) s += hbuf[j] * W2[t * 32 + j];
        zbuf[t] = tanhf(s);
    }
    __syncthreads();
    if (t < 3) {
        const int s = t;
        const float PI = 3.14159265358979323846f;
        float a0 = PI * zbuf[s * 6 + 3], a1 = PI * zbuf[s * 6 + 4], a2 = PI * zbuf[s * 6 + 5];
        float c0 = cosf(a0), s0 = sinf(a0);
        float c1 = cosf(a1), s1 = sinf(a1);
        float c2 = cosf(a2), s2 = sinf(a2);
        float X[3][3] = {{c0, -s0, 0.f}, {s0, c0, 0.f}, {0.f, 0.f, 1.f}};
        float Y[3][3] = {{c1, 0.f, s1}, {0.f, 1.f, 0.f}, {-s1, 0.f, c1}};
        float Z[3][3] = {{1.f, 0.f, 0.f}, {0.f, c2, -s2}, {0.f, s2, c2}};
        float YZ[3][3], M[3][3];
        for (int m = 0; m < 3; ++m)
            for (int n = 0; n < 3; ++n) {
                float v = 0.f;
                for (int k = 0; k < 3; ++k) v += Y[m][k] * Z[k][n];
                YZ[m][n] = v;
            }
        for (int m = 0; m < 3; ++m)
            for (int n = 0; n < 3; ++n) {
                float v = 0.f;
                for (int k = 0; k < 3; ++k) v += X[m][k] * YZ[k][n];
                M[m][n] = v;
                Rl[s][m * 3 + n] = v;
            }
        for (int sd = 0; sd < 3; ++sd)
            Tl[s][sd] = zbuf[s * 6 + 3 + sd] * sz[sd] + center[sd]
                      - (center[0] * M[0][sd] + center[1] * M[1][sd] + center[2] * M[2][sd]);
    }
    __syncthreads();
    const float* xb = x + (size_t)b * 12288;
    float* ob = out + (size_t)b * 12288;
    for (int n = t; n < 2048; n += 256) {
        float px = xb[n], py = xb[2048 + n], pz = xb[4096 + n];
        int s = (n < 20) ? 0 : (n < 40) ? 1 : 2;
        #pragma unroll
        for (int td = 0; td < 3; ++td)
            ob[td * 2048 + n] = Rl[s][0 * 3 + td] * px + Rl[s][1 * 3 + td] * py
                              + Rl[s][2 * 3 + td] * pz + Tl[s][td];
        float c3 = xb[6144 + n], c4 = xb[8192 + n], c5 = xb[10240 + n];
        float mx = fmaxf(c3, fmaxf(c4, c5));
        float e3 = __expf(c3 - mx), e4 = __expf(c4 - mx), e5 = __expf(c5 - mx);
        float inv = 1.f / (e3 + e4 + e5);
        ob[6144 + n] = e3 * inv;
        ob[8192 + n] = e4 * inv;
        ob[10240 + n] = e5 * inv;
    }
}

__global__ __launch_bounds__(256) void k_reg_fb(
    const float* __restrict__ x, const float* __restrict__ A,
    float* __restrict__ out)
{
    const int p = blockIdx.x;
    const int b = blockIdx.y;
    int ci = 0, rem = p;
    while (rem >= 8 - ci) { rem -= 8 - ci; ++ci; }
    const int cj = ci + rem;
    const int t = threadIdx.x;
    __shared__ float4 pj[256];
    __shared__ float4 aj[256];
    const float* xb = x + (size_t)b * 12288;
    {
        int j = cj * 256 + t;
        pj[t] = make_float4(xb[j], xb[2048 + j], xb[4096 + j], 0.f);
        aj[t] = make_float4(A[j], A[2048 + j], A[4096 + j], 0.f);
    }
    __syncthreads();
    const int i = ci * 256 + t;
    const float pix = xb[i], piy = xb[2048 + i], piz = xb[4096 + i];
    const float aix = A[i], aiy = A[2048 + i], aiz = A[4096 + i];
    const int jbase = cj * 256;
    float acc = 0.f;
    #pragma unroll 4
    for (int jj = 0; jj < 256; ++jj) {
        float4 P = pj[jj];
        float4 Q = aj[jj];
        float dx0 = pix - P.x, dy0 = piy - P.y, dz0 = piz - P.z;
        float dxv = sqrtf(dx0 * dx0 + dy0 * dy0 + dz0 * dz0);
        float da0 = aix - Q.x, da1 = aiy - Q.y, da2 = aiz - Q.z;
        float dav = sqrtf(da0 * da0 + da1 * da1 + da2 * da2);
        float d = dav - dxv;
        float dd = (jbase + jj > i) ? d : 0.f;
        acc = fmaf(dd, dd, acc);
    }
    #pragma unroll
    for (int m = 1; m < 64; m <<= 1) acc += __shfl_xor(acc, m);
    __shared__ float wsum[4];
    if ((t & 63) == 0) wsum[t >> 6] = acc;
    __syncthreads();
    if (t == 0) atomicAdd(&out[REG_BASE + b], wsum[0] + wsum[1] + wsum[2] + wsum[3]);
}

__global__ void k_final_fb(float* __restrict__ out)
{
    int b = threadIdx.x;
    if (b < BATCH) out[REG_BASE + b] = sqrtf(2.f * out[REG_BASE + b]);
}

// ===========================================================================
extern "C" void kernel_launch(void* const* d_in, const int* in_sizes, int n_in,
                              void* d_out, int out_size, void* d_ws, size_t ws_size,
                              hipStream_t stream) {
    (void)in_sizes; (void)n_in; (void)out_size;
    const float* x      = (const float*)d_in[0];
    const float* W1     = (const float*)d_in[1];
    const float* b1     = (const float*)d_in[2];
    const float* W2     = (const float*)d_in[3];
    const float* b2     = (const float*)d_in[4];
    const float* A      = (const float*)d_in[5];
    const float* center = (const float*)d_in[6];
    const float* sz     = (const float*)d_in[7];
    float* out = (float*)d_out;
    float* ws  = (float*)d_ws;

    if (ws_size >= WS_BYTES) {
        k_h<<<dim3(4, 16), 256, 0, stream>>>(x, W1, b1, out, ws);
        k_zr<<<1, 64, 0, stream>>>(W2, b2, center, sz, ws);
        k_transform<<<dim3(8, 17), 256, 0, stream>>>(x, A, out, ws);
        k_reg_s<<<dim3(72, 16), 256, 0, stream>>>(ws, out);
        k_final_s<<<1, 64, 0, stream>>>(out, ws);
    } else {
        k_mlp_fb<<<BATCH, 256, 0, stream>>>(x, W1, b1, W2, b2, center, sz, out);
        k_reg_fb<<<dim3(36, 16), 256, 0, stream>>>(x, A, out);
        k_final_fb<<<1, 64, 0, stream>>>(out);
    }
}